// Round 7
// baseline (35.134 us; speedup 1.0000x reference)
//
#include <hip/hip_runtime.h>
#include <math.h>

#define QN 8
#define NDIMS 2
#define LATENT 64
#define OUTC 32     // Q + Q + Q*NDIMS
#define IT 16       // i-rows per block tile in pair kernel

// ---------------------------------------------------------------------------
// Phase 1: feature MLP — 128 THREADS PER POINT: thread = (pt, o, kq).
//   o  = output unit (32), kq = k-quarter (4): each thread computes h[k] for
//   k in [16*kq, 16*kq+16) from per-lane float4 W1/b1 loads (L1-hot, no
//   scalar path) and a 16-long partial dot with W2[o][16*kq..+16).
//   4 partials reduced with 2 shfl_xor; kq==0 lane applies softplus and
//   drops a[o] into 256B of LDS; after one barrier, 8 lanes/point build the
//   derived features (sqrt / sincos) and store.
// 4096 pts * 128 thr = 524288 threads = 8192 waves = 8 waves/SIMD -> the
// L1/K$ latency that capped every previous variant (<=2 waves/SIMD) is
// finally hidden by TLP.
// Store per point (32 floats):
//   [0:8) u = w*sqrt(s)*2^.25 | [8:16) s^2 | [16:24) cos2pi*phi | [24:32) sin
// ---------------------------------------------------------------------------
__global__ __launch_bounds__(256) void feat_kernel(
    const float* __restrict__ x, const float* __restrict__ y, int n,
    const float* __restrict__ W1, const float* __restrict__ b1,
    const float* __restrict__ W2, const float* __restrict__ b2,
    float* __restrict__ featX, float* __restrict__ featY)
{
    __shared__ float a_lds[2][OUTC];          // 2 points per 256-thread block

    const int local = threadIdx.x;            // 0..255
    const int ptb   = local >> 7;             // 0/1: point within block
    const int r     = local & 127;
    const int o     = r >> 2;                 // 0..31 output unit
    const int kq    = r & 3;                  // 0..3 k-quarter
    const int npts  = 2 * n;
    const int gp    = blockIdx.x * 2 + ptb;
    const int gpc   = (gp < npts) ? gp : (npts - 1);   // clamp; no early return

    const float* p = (gpc < n) ? (x + 2 * gpc) : (y + 2 * (gpc - n));
    const float p0 = p[0], p1 = p[1];

    const float kScale = 1.0507009873554804934193349852946f;
    const float kAlpha = 1.6732632423543772848170429916717f;

    // --- partial dot over k in [16kq, 16kq+16): all loads per-lane float4 ---
    const float4* w1v = (const float4*)(W1 + kq * 32);   // 16 (w0,w1) pairs
    const float4* b1v = (const float4*)(b1 + kq * 16);
    const float4* w2v = (const float4*)(W2 + o * LATENT + kq * 16);

    float acc = (kq == 0) ? b2[o] : 0.f;
    #pragma unroll
    for (int g = 0; g < 4; ++g) {             // 4 h-units per group
        float4 wa = w1v[2 * g];               // W1 rows 4g..4g+1
        float4 wb = w1v[2 * g + 1];           // W1 rows 4g+2..4g+3
        float4 bb = b1v[g];
        float z0 = fmaf(wa.x, p0, fmaf(wa.y, p1, bb.x));
        float z1 = fmaf(wa.z, p0, fmaf(wa.w, p1, bb.y));
        float z2 = fmaf(wb.x, p0, fmaf(wb.y, p1, bb.z));
        float z3 = fmaf(wb.z, p0, fmaf(wb.w, p1, bb.w));
        float h0 = kScale * (z0 > 0.f ? z0 : kAlpha * (__expf(z0) - 1.f));
        float h1 = kScale * (z1 > 0.f ? z1 : kAlpha * (__expf(z1) - 1.f));
        float h2 = kScale * (z2 > 0.f ? z2 : kAlpha * (__expf(z2) - 1.f));
        float h3 = kScale * (z3 > 0.f ? z3 : kAlpha * (__expf(z3) - 1.f));
        float4 w2q = w2v[g];
        acc = fmaf(w2q.x, h0, fmaf(w2q.y, h1, fmaf(w2q.z, h2, fmaf(w2q.w, h3, acc))));
    }
    // --- reduce the 4 k-quarters (lanes o*4+kq are wave-contiguous) ---
    acc += __shfl_xor(acc, 1, 64);
    acc += __shfl_xor(acc, 2, 64);
    if (kq == 0) {
        // stable softplus: max(z,0) + log(1 + exp(-|z|))
        a_lds[ptb][o] = fmaxf(acc, 0.f) + __logf(1.f + __expf(-fabsf(acc)));
    }
    __syncthreads();

    // --- stage C: 8 lanes per point build derived features and store ---
    if ((r < 8) && (gp < npts)) {
        const int q = r;
        float w_ = a_lds[ptb][q];
        float s_ = a_lds[ptb][QN + q];
        float f0 = a_lds[ptb][2 * QN + 2 * q];
        float f1 = a_lds[ptb][2 * QN + 2 * q + 1];
        const float TWO_PI  = 6.283185307179586f;
        const float ROOT4_2 = 1.18920711500272107f;   // 2^(1/4)
        float phi = fmaf(f0, p0, f1 * p1);
        float rr  = phi - floorf(phi);                // [0,1) revolutions
        float ang = TWO_PI * rr;
        float* fo = (gp < n) ? (featX + 32 * gp) : (featY + 32 * (gp - n));
        fo[q]          = w_ * sqrtf(s_) * ROOT4_2;
        fo[QN + q]     = s_ * s_;
        fo[2 * QN + q] = __cosf(ang);
        fo[3 * QN + q] = __sinf(ang);
    }
}

// ---------------------------------------------------------------------------
// Phase 2: pairwise kernel — BYTE-IDENTICAL to round 6 (~2 us, at the write
// floor per the r5->r6 ledger; clean differential for the feat change).
// ---------------------------------------------------------------------------
__global__ __launch_bounds__(256) void pair_kernel(
    const float* __restrict__ x, const float* __restrict__ y, int n,
    const float* __restrict__ fA, const float* __restrict__ fB,
    float* __restrict__ out)
{
    __shared__ __align__(16) float faS[IT * 32];   // 2 KB: 32 feats per i
    __shared__ __align__(16) float xaS[IT * 2];    // (x0,x1) per i

    const int tid = threadIdx.x;
    const int j   = blockIdx.x * 256 + tid;
    const int i0  = blockIdx.y * IT;

    if (tid < IT * 8) {                                 // 128 float4s of fA
        ((float4*)faS)[tid] = ((const float4*)(fA + (size_t)i0 * 32))[tid];
    } else if (tid < IT * 8 + IT / 2) {                 // 8 float4s of x
        ((float4*)xaS)[tid - IT * 8] = ((const float4*)(x + 2 * i0))[tid - IT * 8];
    }
    __syncthreads();

    if (j >= n) return;     // no barriers after this point

    const float4* fb4 = (const float4*)(fB + 32 * j);
    float4 fu0 = fb4[0], fu1 = fb4[1];
    float4 fs0 = fb4[2], fs1 = fb4[3];
    float4 fc0 = fb4[4], fc1 = fb4[5];
    float4 fn0 = fb4[6], fn1 = fb4[7];
    float uB[QN]  = {fu0.x,fu0.y,fu0.z,fu0.w, fu1.x,fu1.y,fu1.z,fu1.w};
    float ssB[QN] = {fs0.x,fs0.y,fs0.z,fs0.w, fs1.x,fs1.y,fs1.z,fs1.w};
    float cB[QN]  = {fc0.x,fc0.y,fc0.z,fc0.w, fc1.x,fc1.y,fc1.z,fc1.w};
    float snB[QN] = {fn0.x,fn0.y,fn0.z,fn0.w, fn1.x,fn1.y,fn1.z,fn1.w};

    float2 yv = *(const float2*)(y + 2 * j);
    const float LOG2E = 1.4426950408889634f;

    #pragma unroll 2
    for (int ii = 0; ii < IT; ++ii) {
        int i = i0 + ii;
        if (i >= n) break;

        const float4* fa4 = (const float4*)(faS + ii * 32);
        float4 au0 = fa4[0], au1 = fa4[1];
        float4 as0 = fa4[2], as1 = fa4[3];
        float4 ac0 = fa4[4], ac1 = fa4[5];
        float4 an0 = fa4[6], an1 = fa4[7];
        float uA[QN]  = {au0.x,au0.y,au0.z,au0.w, au1.x,au1.y,au1.z,au1.w};
        float ssA[QN] = {as0.x,as0.y,as0.z,as0.w, as1.x,as1.y,as1.z,as1.w};
        float cA[QN]  = {ac0.x,ac0.y,ac0.z,ac0.w, ac1.x,ac1.y,ac1.z,ac1.w};
        float snA[QN] = {an0.x,an0.y,an0.z,an0.w, an1.x,an1.y,an1.z,an1.w};

        float dx  = xaS[2 * ii]     - yv.x;
        float dy  = xaS[2 * ii + 1] - yv.y;
        float d2l = fmaf(dx, dx, dy * dy) * LOG2E;   // d2 * log2(e)

        float acc = 0.f;
        #pragma unroll
        for (int q = 0; q < QN; ++q) {
            float s2  = ssA[q] + ssB[q];
            float inv = __builtin_amdgcn_rcpf(s2);
            float e   = __builtin_amdgcn_exp2f(-d2l * inv);   // exp(-d2/s2)
            float g   = uA[q] * uB[q] * inv * e;
            float c   = fmaf(cA[q], cB[q], snA[q] * snB[q]);
            acc = fmaf(g, c, acc);
        }
        out[(long)i * n + j] = acc;
    }
}

extern "C" void kernel_launch(void* const* d_in, const int* in_sizes, int n_in,
                              void* d_out, int out_size, void* d_ws, size_t ws_size,
                              hipStream_t stream)
{
    const float* x  = (const float*)d_in[0];
    const float* y  = (const float*)d_in[1];
    const float* W1 = (const float*)d_in[2];
    const float* b1 = (const float*)d_in[3];
    const float* W2 = (const float*)d_in[4];
    const float* b2 = (const float*)d_in[5];
    float* out = (float*)d_out;

    int n = in_sizes[0] / NDIMS;     // 2048

    float* featX = (float*)d_ws;
    float* featY = featX + (size_t)n * 32;

    int npts = 2 * n;
    // 128 threads per point, 2 points per 256-thread block
    hipLaunchKernelGGL(feat_kernel, dim3((npts + 1) / 2), dim3(256), 0, stream,
                       x, y, n, W1, b1, W2, b2, featX, featY);

    dim3 grid((n + 255) / 256, (n + IT - 1) / IT);
    hipLaunchKernelGGL(pair_kernel, grid, dim3(256), 0, stream,
                       x, y, n, featX, featY, out);
}

// Round 8
// 29.768 us; speedup vs baseline: 1.1803x; 1.1803x over previous
//
#include <hip/hip_runtime.h>
#include <math.h>

#define QN 8
#define NDIMS 2
#define LATENT 64
#define OUTC 32     // Q + Q + Q*NDIMS
#define IT 8        // i-rows per block tile in pair kernel
#define JPT 4       // j's per thread in pair kernel

// ---------------------------------------------------------------------------
// Phase 1: feature MLP. thread = (pt, o); 8 points per 256-thread block.
//  * W2 staged TRANSPOSED in LDS as float2 w2p[kk][o] (kk = k/2): compute
//    reads are lane-contiguous ds_read_b64 (2-way bank alias = free), so no
//    per-lane L1 gathers and no W2 s_load chain.
//  * h[k] computed 4-at-a-time interleaved with the dot: 1 live h-group,
//    ~40 VGPR, no spill. W1/b1 via K$-hot s_loads, hidden by 8 waves/CU.
//  * epilogue: 2 shuffles give every lane what it needs; ALL 32 lanes store
//    one dword -> fully coalesced 128B per point.
// Store per point (32 floats):
//   [0:8) u=w*sqrt(s)*2^.25 | [8:16) s^2 | [16:24) cos 2pi*phi | [24:32) sin
// ---------------------------------------------------------------------------
__global__ __launch_bounds__(256) void feat_kernel(
    const float* __restrict__ x, const float* __restrict__ y, int n,
    const float* __restrict__ W1, const float* __restrict__ b1,
    const float* __restrict__ W2, const float* __restrict__ b2,
    float* __restrict__ featX, float* __restrict__ featY)
{
    __shared__ float2 w2p[LATENT / 2][OUTC];   // [kk][o], 8 KB

    const int tid = threadIdx.x;
    const int o   = tid & 31;

    // ---- stage W2 transposed: thread (k8, o) moves W2[o][8k8 .. 8k8+8) ----
    {
        const int k8 = tid >> 5;                       // 0..7
        const float4* src = (const float4*)(W2 + o * LATENT + 8 * k8);
        float4 a0 = src[0], a1 = src[1];
        w2p[4 * k8 + 0][o] = make_float2(a0.x, a0.y);
        w2p[4 * k8 + 1][o] = make_float2(a0.z, a0.w);
        w2p[4 * k8 + 2][o] = make_float2(a1.x, a1.y);
        w2p[4 * k8 + 3][o] = make_float2(a1.z, a1.w);
    }
    __syncthreads();

    const int npts = 2 * n;
    int gp = blockIdx.x * 8 + (tid >> 5);
    if (gp >= npts) gp = npts - 1;                     // clamp (no early ret)

    const float* p = (gp < n) ? (x + 2 * gp) : (y + 2 * (gp - n));
    float2 pv = *(const float2*)p;
    const float p0 = pv.x, p1 = pv.y;

    const float kScale = 1.0507009873554804934193349852946f;
    const float kAlpha = 1.6732632423543772848170429916717f;

    float acc0 = b2[o], acc1 = 0.f, acc2 = 0.f, acc3 = 0.f;
    #pragma unroll
    for (int kb = 0; kb < 16; ++kb) {                  // 4 k's per iter
        float4 wa = ((const float4*)W1)[2 * kb];       // W1 rows 4kb,4kb+1
        float4 wb = ((const float4*)W1)[2 * kb + 1];   // rows 4kb+2,4kb+3
        float4 bb = ((const float4*)b1)[kb];
        float z0 = fmaf(wa.x, p0, fmaf(wa.y, p1, bb.x));
        float z1 = fmaf(wa.z, p0, fmaf(wa.w, p1, bb.y));
        float z2 = fmaf(wb.x, p0, fmaf(wb.y, p1, bb.z));
        float z3 = fmaf(wb.z, p0, fmaf(wb.w, p1, bb.w));
        float h0 = kScale * (z0 > 0.f ? z0 : kAlpha * (__expf(z0) - 1.f));
        float h1 = kScale * (z1 > 0.f ? z1 : kAlpha * (__expf(z1) - 1.f));
        float h2 = kScale * (z2 > 0.f ? z2 : kAlpha * (__expf(z2) - 1.f));
        float h3 = kScale * (z3 > 0.f ? z3 : kAlpha * (__expf(z3) - 1.f));
        float2 wlo = w2p[2 * kb][o];                   // W2[o][4kb..4kb+2)
        float2 whi = w2p[2 * kb + 1][o];               // W2[o][4kb+2..4kb+4)
        acc0 = fmaf(wlo.x, h0, acc0);
        acc1 = fmaf(wlo.y, h1, acc1);
        acc2 = fmaf(whi.x, h2, acc2);
        acc3 = fmaf(whi.y, h3, acc3);
    }
    float z = (acc0 + acc1) + (acc2 + acc3);
    // stable softplus: max(z,0) + log(1 + exp(-|z|))
    float av = fmaxf(z, 0.f) + __logf(1.f + __expf(-fabsf(z)));

    // ---- distribute: lane o emits output element o for its point ----------
    const int lane = tid & 63;
    const int base = lane & 32;                        // point within wave
    int src1, src2;
    if (o < 8)       { src1 = o + 8;      src2 = o; }          // s for u-lane
    else if (o < 16) { src1 = o;          src2 = o; }          // own only
    else if (o < 24) { src1 = 2 * o - 16; src2 = 2 * o - 15; } // f0,f1 (cos)
    else             { src1 = 2 * o - 32; src2 = 2 * o - 31; } // f0,f1 (sin)
    float v1 = __shfl(av, base + src1, 64);
    float v2 = __shfl(av, base + src2, 64);

    const float TWO_PI  = 6.283185307179586f;
    const float ROOT4_2 = 1.18920711500272107f;        // 2^(1/4)
    float val;
    if (o < 8) {
        val = av * sqrtf(v1) * ROOT4_2;                // u = w*sqrt(s)*2^.25
    } else if (o < 16) {
        val = av * av;                                 // s^2
    } else {
        float phi = fmaf(v1, p0, v2 * p1);
        float rr  = phi - floorf(phi);                 // [0,1) revolutions
        float ang = TWO_PI * rr;
        val = (o < 24) ? __cosf(ang) : __sinf(ang);
    }
    float* fo = (gp < n) ? (featX + 32 * gp) : (featY + 32 * (gp - n));
    fo[o] = val;                                       // coalesced 128B/point
}

// ---------------------------------------------------------------------------
// Phase 2: pairwise kernel — JPT=4 j's per thread, IT=8 i's per block.
// LDS wave-instructions per CU drop 4x vs r6 (was the 10us LDS-pipe bound);
// new bound is VALU+trans (~4.7us model). float4 output stores.
// ---------------------------------------------------------------------------
__global__ __launch_bounds__(256) void pair_kernel(
    const float* __restrict__ x, const float* __restrict__ y, int n,
    const float* __restrict__ fA, const float* __restrict__ fB,
    float* __restrict__ out)
{
    __shared__ __align__(16) float faS[IT * 32];       // 1 KB
    __shared__ __align__(16) float xaS[IT * 2];        // 64 B

    const int tid = threadIdx.x;
    const int i0  = blockIdx.y * IT;

    // ---- cooperative stage of the i-tile ----
    if (tid < IT * 8) {
        ((float4*)faS)[tid] = ((const float4*)(fA + (size_t)i0 * 32))[tid];
    } else if (tid < IT * 8 + IT / 2) {
        ((float4*)xaS)[tid - IT * 8] = ((const float4*)(x + 2 * i0))[tid - IT * 8];
    }
    __syncthreads();

    const int j0 = blockIdx.x * (256 * JPT) + tid * JPT;   // 4 contiguous j's
    if (j0 >= n) return;

    // ---- B-side features for 4 j's into registers (static indices) --------
    float uB[JPT][QN], ssB[JPT][QN], cB[JPT][QN], snB[JPT][QN];
    float yj0[JPT], yj1[JPT];
    #pragma unroll
    for (int jj = 0; jj < JPT; ++jj) {
        const float4* fb4 = (const float4*)(fB + 32 * (j0 + jj));
        float4 a0 = fb4[0], a1 = fb4[1], a2 = fb4[2], a3 = fb4[3];
        float4 a4 = fb4[4], a5 = fb4[5], a6 = fb4[6], a7 = fb4[7];
        uB[jj][0]=a0.x; uB[jj][1]=a0.y; uB[jj][2]=a0.z; uB[jj][3]=a0.w;
        uB[jj][4]=a1.x; uB[jj][5]=a1.y; uB[jj][6]=a1.z; uB[jj][7]=a1.w;
        ssB[jj][0]=a2.x; ssB[jj][1]=a2.y; ssB[jj][2]=a2.z; ssB[jj][3]=a2.w;
        ssB[jj][4]=a3.x; ssB[jj][5]=a3.y; ssB[jj][6]=a3.z; ssB[jj][7]=a3.w;
        cB[jj][0]=a4.x; cB[jj][1]=a4.y; cB[jj][2]=a4.z; cB[jj][3]=a4.w;
        cB[jj][4]=a5.x; cB[jj][5]=a5.y; cB[jj][6]=a5.z; cB[jj][7]=a5.w;
        snB[jj][0]=a6.x; snB[jj][1]=a6.y; snB[jj][2]=a6.z; snB[jj][3]=a6.w;
        snB[jj][4]=a7.x; snB[jj][5]=a7.y; snB[jj][6]=a7.z; snB[jj][7]=a7.w;
        float2 yv = *(const float2*)(y + 2 * (j0 + jj));
        yj0[jj] = yv.x; yj1[jj] = yv.y;
    }

    const float NLOG2E = -1.4426950408889634f;

    #pragma unroll 2
    for (int ii = 0; ii < IT; ++ii) {
        int i = i0 + ii;
        if (i >= n) break;

        // broadcast ds_read_b128 of this i's features (all lanes same addr)
        const float4* fa4 = (const float4*)(faS + ii * 32);
        float4 b0 = fa4[0], b1v = fa4[1], b2v = fa4[2], b3 = fa4[3];
        float4 b4 = fa4[4], b5 = fa4[5], b6 = fa4[6], b7 = fa4[7];
        float uA[QN]  = {b0.x,b0.y,b0.z,b0.w, b1v.x,b1v.y,b1v.z,b1v.w};
        float ssA[QN] = {b2v.x,b2v.y,b2v.z,b2v.w, b3.x,b3.y,b3.z,b3.w};
        float cA[QN]  = {b4.x,b4.y,b4.z,b4.w, b5.x,b5.y,b5.z,b5.w};
        float snA[QN] = {b6.x,b6.y,b6.z,b6.w, b7.x,b7.y,b7.z,b7.w};
        float xi0 = xaS[2 * ii], xi1 = xaS[2 * ii + 1];

        float d2ln[JPT];
        #pragma unroll
        for (int jj = 0; jj < JPT; ++jj) {
            float dx = xi0 - yj0[jj];
            float dy = xi1 - yj1[jj];
            d2ln[jj] = fmaf(dx, dx, dy * dy) * NLOG2E;   // -d2*log2(e)
        }

        float4 accv;
        float* accp = &accv.x;
        #pragma unroll
        for (int jj = 0; jj < JPT; ++jj) {
            float acc = 0.f;
            #pragma unroll
            for (int q = 0; q < QN; ++q) {
                float s2  = ssA[q] + ssB[jj][q];
                float inv = __builtin_amdgcn_rcpf(s2);
                float e   = __builtin_amdgcn_exp2f(d2ln[jj] * inv);
                float t   = uA[q] * uB[jj][q];
                float c   = fmaf(cA[q], cB[jj][q], snA[q] * snB[jj][q]);
                acc = fmaf(t * inv * e, c, acc);
            }
            accp[jj] = acc;
        }
        *(float4*)(out + (long)i * n + j0) = accv;
    }
}

extern "C" void kernel_launch(void* const* d_in, const int* in_sizes, int n_in,
                              void* d_out, int out_size, void* d_ws, size_t ws_size,
                              hipStream_t stream)
{
    const float* x  = (const float*)d_in[0];
    const float* y  = (const float*)d_in[1];
    const float* W1 = (const float*)d_in[2];
    const float* b1 = (const float*)d_in[3];
    const float* W2 = (const float*)d_in[4];
    const float* b2 = (const float*)d_in[5];
    float* out = (float*)d_out;

    int n = in_sizes[0] / NDIMS;     // 2048

    float* featX = (float*)d_ws;
    float* featY = featX + (size_t)n * 32;

    int npts = 2 * n;
    // 32 threads per point, 8 points per 256-thread block
    hipLaunchKernelGGL(feat_kernel, dim3((npts + 7) / 8), dim3(256), 0, stream,
                       x, y, n, W1, b1, W2, b2, featX, featY);

    dim3 grid((n + 256 * JPT - 1) / (256 * JPT), (n + IT - 1) / IT);
    hipLaunchKernelGGL(pair_kernel, grid, dim3(256), 0, stream,
                       x, y, n, featX, featY, out);
}

// Round 9
// 28.922 us; speedup vs baseline: 1.2148x; 1.0292x over previous
//
#include <hip/hip_runtime.h>
#include <math.h>

#define QN 8
#define NDIMS 2
#define LATENT 64
#define OUTC 32     // Q + Q + Q*NDIMS
#define IT 8        // i-rows per block tile in pair kernel
#define JPT 4       // j's per thread in pair kernel

// ---------------------------------------------------------------------------
// Phase 1: feature MLP — BYTE-IDENTICAL to round 5/6 (the best-total feat).
// One thread per (point, output-unit); 2048 waves; no LDS/barriers/spills.
// Store per point (32 floats):
//   [0:8) u=w*sqrt(s)*2^.25 | [8:16) s^2 | [16:24) cos 2pi*phi | [24:32) sin
// ---------------------------------------------------------------------------
__global__ __launch_bounds__(256) void feat_kernel(
    const float* __restrict__ x, const float* __restrict__ y, int n,
    const float* __restrict__ W1, const float* __restrict__ b1,
    const float* __restrict__ W2, const float* __restrict__ b2,
    float* __restrict__ featX, float* __restrict__ featY)
{
    const int t    = blockIdx.x * 256 + threadIdx.x;
    const int pt   = t >> 5;                 // point index (2 points per wave)
    const int o    = t & 31;                 // output unit for this lane
    const int npts = 2 * n;
    if (pt >= npts) return;

    const float* p = (pt < n) ? (x + 2 * pt) : (y + 2 * (pt - n));
    float p0 = p[0], p1 = p[1];

    const float kScale = 1.0507009873554804934193349852946f;
    const float kAlpha = 1.6732632423543772848170429916717f;

    const float4* w2v = (const float4*)(W2 + o * LATENT);
    float z0 = b2[o], z1 = 0.f, z2 = 0.f, z3 = 0.f;
    #pragma unroll
    for (int c = 0; c < LATENT / 16; ++c) {
        float hb[16];
        #pragma unroll
        for (int r = 0; r < 16; ++r) {
            int k = 16 * c + r;
            float zz = fmaf(W1[2 * k], p0, fmaf(W1[2 * k + 1], p1, b1[k]));
            hb[r] = kScale * (zz > 0.f ? zz : kAlpha * (__expf(zz) - 1.f));
        }
        float4 w0 = w2v[4 * c + 0];
        float4 w1v = w2v[4 * c + 1];
        float4 w2q = w2v[4 * c + 2];
        float4 w3 = w2v[4 * c + 3];
        z0 = fmaf(w0.x,  hb[0],  fmaf(w0.y,  hb[1],  fmaf(w0.z,  hb[2],  fmaf(w0.w,  hb[3],  z0))));
        z1 = fmaf(w1v.x, hb[4],  fmaf(w1v.y, hb[5],  fmaf(w1v.z, hb[6],  fmaf(w1v.w, hb[7],  z1))));
        z2 = fmaf(w2q.x, hb[8],  fmaf(w2q.y, hb[9],  fmaf(w2q.z, hb[10], fmaf(w2q.w, hb[11], z2))));
        z3 = fmaf(w3.x,  hb[12], fmaf(w3.y,  hb[13], fmaf(w3.z,  hb[14], fmaf(w3.w,  hb[15], z3))));
    }
    float z = (z0 + z1) + (z2 + z3);
    float av = fmaxf(z, 0.f) + __logf(1.f + __expf(-fabsf(z)));

    const int lane = threadIdx.x & 63;
    const int base = lane & 32;               // half-wave owning this point
    const int q    = lane & 7;
    float w_ = __shfl(av, base + q, 64);
    float s_ = __shfl(av, base + 8 + q, 64);
    float f0 = __shfl(av, base + 16 + 2 * q, 64);
    float f1 = __shfl(av, base + 17 + 2 * q, 64);

    if ((lane & 31) < 8) {
        const float TWO_PI  = 6.283185307179586f;
        const float ROOT4_2 = 1.18920711500272107f;   // 2^(1/4)
        float phi = fmaf(f0, p0, f1 * p1);
        float rr  = phi - floorf(phi);
        float ang = TWO_PI * rr;
        float* fo = (pt < n) ? (featX + 32 * pt) : (featY + 32 * (pt - n));
        fo[q]          = w_ * sqrtf(s_) * ROOT4_2;
        fo[QN + q]     = s_ * s_;
        fo[2 * QN + q] = __cosf(ang);
        fo[3 * QN + q] = __sinf(ang);
    }
}

// ---------------------------------------------------------------------------
// Phase 2: pairwise kernel — BYTE-IDENTICAL to round 8 (JPT=4, IT=8).
// Model: VALU/trans-bound ~4.7us (LDS traffic amortized 4x vs pair_v1).
// ---------------------------------------------------------------------------
__global__ __launch_bounds__(256) void pair_kernel(
    const float* __restrict__ x, const float* __restrict__ y, int n,
    const float* __restrict__ fA, const float* __restrict__ fB,
    float* __restrict__ out)
{
    __shared__ __align__(16) float faS[IT * 32];       // 1 KB
    __shared__ __align__(16) float xaS[IT * 2];        // 64 B

    const int tid = threadIdx.x;
    const int i0  = blockIdx.y * IT;

    // ---- cooperative stage of the i-tile ----
    if (tid < IT * 8) {
        ((float4*)faS)[tid] = ((const float4*)(fA + (size_t)i0 * 32))[tid];
    } else if (tid < IT * 8 + IT / 2) {
        ((float4*)xaS)[tid - IT * 8] = ((const float4*)(x + 2 * i0))[tid - IT * 8];
    }
    __syncthreads();

    const int j0 = blockIdx.x * (256 * JPT) + tid * JPT;   // 4 contiguous j's
    if (j0 >= n) return;

    // ---- B-side features for 4 j's into registers (static indices) --------
    float uB[JPT][QN], ssB[JPT][QN], cB[JPT][QN], snB[JPT][QN];
    float yj0[JPT], yj1[JPT];
    #pragma unroll
    for (int jj = 0; jj < JPT; ++jj) {
        const float4* fb4 = (const float4*)(fB + 32 * (j0 + jj));
        float4 a0 = fb4[0], a1 = fb4[1], a2 = fb4[2], a3 = fb4[3];
        float4 a4 = fb4[4], a5 = fb4[5], a6 = fb4[6], a7 = fb4[7];
        uB[jj][0]=a0.x; uB[jj][1]=a0.y; uB[jj][2]=a0.z; uB[jj][3]=a0.w;
        uB[jj][4]=a1.x; uB[jj][5]=a1.y; uB[jj][6]=a1.z; uB[jj][7]=a1.w;
        ssB[jj][0]=a2.x; ssB[jj][1]=a2.y; ssB[jj][2]=a2.z; ssB[jj][3]=a2.w;
        ssB[jj][4]=a3.x; ssB[jj][5]=a3.y; ssB[jj][6]=a3.z; ssB[jj][7]=a3.w;
        cB[jj][0]=a4.x; cB[jj][1]=a4.y; cB[jj][2]=a4.z; cB[jj][3]=a4.w;
        cB[jj][4]=a5.x; cB[jj][5]=a5.y; cB[jj][6]=a5.z; cB[jj][7]=a5.w;
        snB[jj][0]=a6.x; snB[jj][1]=a6.y; snB[jj][2]=a6.z; snB[jj][3]=a6.w;
        snB[jj][4]=a7.x; snB[jj][5]=a7.y; snB[jj][6]=a7.z; snB[jj][7]=a7.w;
        float2 yv = *(const float2*)(y + 2 * (j0 + jj));
        yj0[jj] = yv.x; yj1[jj] = yv.y;
    }

    const float NLOG2E = -1.4426950408889634f;

    #pragma unroll 2
    for (int ii = 0; ii < IT; ++ii) {
        int i = i0 + ii;
        if (i >= n) break;

        const float4* fa4 = (const float4*)(faS + ii * 32);
        float4 b0 = fa4[0], b1v = fa4[1], b2v = fa4[2], b3 = fa4[3];
        float4 b4 = fa4[4], b5 = fa4[5], b6 = fa4[6], b7 = fa4[7];
        float uA[QN]  = {b0.x,b0.y,b0.z,b0.w, b1v.x,b1v.y,b1v.z,b1v.w};
        float ssA[QN] = {b2v.x,b2v.y,b2v.z,b2v.w, b3.x,b3.y,b3.z,b3.w};
        float cA[QN]  = {b4.x,b4.y,b4.z,b4.w, b5.x,b5.y,b5.z,b5.w};
        float snA[QN] = {b6.x,b6.y,b6.z,b6.w, b7.x,b7.y,b7.z,b7.w};
        float xi0 = xaS[2 * ii], xi1 = xaS[2 * ii + 1];

        float d2ln[JPT];
        #pragma unroll
        for (int jj = 0; jj < JPT; ++jj) {
            float dx = xi0 - yj0[jj];
            float dy = xi1 - yj1[jj];
            d2ln[jj] = fmaf(dx, dx, dy * dy) * NLOG2E;   // -d2*log2(e)
        }

        float4 accv;
        float* accp = &accv.x;
        #pragma unroll
        for (int jj = 0; jj < JPT; ++jj) {
            float acc = 0.f;
            #pragma unroll
            for (int q = 0; q < QN; ++q) {
                float s2  = ssA[q] + ssB[jj][q];
                float inv = __builtin_amdgcn_rcpf(s2);
                float e   = __builtin_amdgcn_exp2f(d2ln[jj] * inv);
                float t   = uA[q] * uB[jj][q];
                float c   = fmaf(cA[q], cB[jj][q], snA[q] * snB[jj][q]);
                acc = fmaf(t * inv * e, c, acc);
            }
            accp[jj] = acc;
        }
        *(float4*)(out + (long)i * n + j0) = accv;
    }
}

extern "C" void kernel_launch(void* const* d_in, const int* in_sizes, int n_in,
                              void* d_out, int out_size, void* d_ws, size_t ws_size,
                              hipStream_t stream)
{
    const float* x  = (const float*)d_in[0];
    const float* y  = (const float*)d_in[1];
    const float* W1 = (const float*)d_in[2];
    const float* b1 = (const float*)d_in[3];
    const float* W2 = (const float*)d_in[4];
    const float* b2 = (const float*)d_in[5];
    float* out = (float*)d_out;

    int n = in_sizes[0] / NDIMS;     // 2048

    float* featX = (float*)d_ws;
    float* featY = featX + (size_t)n * 32;

    int npts = 2 * n;
    int featThreads = npts * OUTC;                    // one thread per (pt, o)
    hipLaunchKernelGGL(feat_kernel, dim3((featThreads + 255) / 256), dim3(256), 0, stream,
                       x, y, n, W1, b1, W2, b2, featX, featY);

    dim3 grid((n + 256 * JPT - 1) / (256 * JPT), (n + IT - 1) / IT);
    hipLaunchKernelGGL(pair_kernel, grid, dim3(256), 0, stream,
                       x, y, n, featX, featY, out);
}